// Round 1
// baseline (300.118 us; speedup 1.0000x reference)
//
#include <hip/hip_runtime.h>
#include <math.h>

#define S_LEN 512
#define D_DIM 256
#define SLICE (S_LEN * D_DIM)   // 131072

typedef _Float16 half8  __attribute__((ext_vector_type(8)));
typedef _Float16 half4v __attribute__((ext_vector_type(4)));
typedef float   floatx4 __attribute__((ext_vector_type(4)));

// ---------------------------------------------------------------------------
// WlhT[d][e] = fp16(Wl[e][d] + (e==d))     (raw + raw@Wl == raw@(I+Wl))
// ---------------------------------------------------------------------------
__global__ __launch_bounds__(256) void prep_wl(const float* __restrict__ Wl,
                                               _Float16* __restrict__ WlhT)
{
    const int d = blockIdx.x, e = threadIdx.x;
    float v = Wl[e * D_DIM + d] + (e == d ? 1.0f : 0.0f);
    WlhT[d * D_DIM + e] = (_Float16)v;
}

// ---------------------------------------------------------------------------
// y = x + x@W + b  for [512,256]@[256,256].
// k,q results are consumed ONLY as fp16 downstream -> cast at the store
// (identical rounding to the old fp32-store + cvt kernel; saves a kernel
// and a 2MB round-trip). v stays fp32. 2 rows/block -> 768 blocks (3/CU).
// ---------------------------------------------------------------------------
__global__ __launch_bounds__(256) void linres3(
    const float* __restrict__ xk, const float* __restrict__ Wk,
    const float* __restrict__ bk, _Float16* __restrict__ yk16,
    const float* __restrict__ xq, const float* __restrict__ Wq,
    const float* __restrict__ bq, _Float16* __restrict__ yq16,
    const float* __restrict__ xv, const float* __restrict__ Wv,
    const float* __restrict__ bv, float* __restrict__ yv)
{
    __shared__ float xs[2][D_DIM];
    const int r0 = blockIdx.x * 2;
    const int sel = blockIdx.y;
    const float* x = sel == 0 ? xk : (sel == 1 ? xq : xv);
    const float* W = sel == 0 ? Wk : (sel == 1 ? Wq : Wv);
    const float* b = sel == 0 ? bk : (sel == 1 ? bq : bv);

    const int tid = threadIdx.x;
    #pragma unroll
    for (int t = 0; t < 2; ++t) xs[t][tid] = x[(r0 + t) * D_DIM + tid];
    __syncthreads();
    const float bv_ = b[tid];
    float acc[2];
    #pragma unroll
    for (int i = 0; i < 2; ++i) acc[i] = xs[i][tid] + bv_;
    #pragma unroll 4
    for (int e = 0; e < D_DIM; ++e) {
        const float w = W[e * D_DIM + tid];
        #pragma unroll
        for (int i = 0; i < 2; ++i) acc[i] += xs[i][e] * w;
    }
    if (sel == 2) {
        #pragma unroll
        for (int i = 0; i < 2; ++i) yv[(r0 + i) * D_DIM + tid] = acc[i];
    } else {
        _Float16* y16 = sel == 0 ? yk16 : yq16;
        #pragma unroll
        for (int i = 0; i < 2; ++i) y16[(r0 + i) * D_DIM + tid] = (_Float16)acc[i];
    }
}

// ---------------------------------------------------------------------------
// Final linear with partial-sum fusion: x = sum_c po[c]; out = x + x@W + b
// 2 rows/block -> 256 blocks (was 128 = 0.5 blocks/CU).
// ---------------------------------------------------------------------------
__global__ __launch_bounds__(256) void linres_sum(
    const float* __restrict__ po, const float* __restrict__ W,
    const float* __restrict__ b, float* __restrict__ y)
{
    __shared__ float xs[2][D_DIM];
    const int tid = threadIdx.x;
    const int r0  = blockIdx.x * 2;
    #pragma unroll
    for (int t = 0; t < 2; ++t) {
        float s = 0.f;
        #pragma unroll
        for (int c = 0; c < 16; ++c)
            s += po[(size_t)c * SLICE + (r0 + t) * D_DIM + tid];
        xs[t][tid] = s;
    }
    __syncthreads();
    const float bv_ = b[tid];
    float acc[2];
    #pragma unroll
    for (int i = 0; i < 2; ++i) acc[i] = xs[i][tid] + bv_;
    #pragma unroll 4
    for (int e = 0; e < D_DIM; ++e) {
        const float w = W[e * D_DIM + tid];
        #pragma unroll
        for (int i = 0; i < 2; ++i) acc[i] += xs[i][e] * w;
    }
    #pragma unroll
    for (int i = 0; i < 2; ++i) y[(r0 + i) * D_DIM + tid] = acc[i];
}

// ---------------------------------------------------------------------------
// Stage 64x256 fp16 q tile into fragment-major LDS (R3/R7/R11-proven):
// fb = mt*8+kk; slot = quad*16+l16; addr16 = fb*64 + slot. Conflict-free.
// ---------------------------------------------------------------------------
__device__ __forceinline__ void stage_q(const _Float16* __restrict__ qh,
                                        _Float16* __restrict__ Afrag,
                                        int sq0, int tid)
{
    const int i   = tid & 63;   // row within tile
    const int qtr = tid >> 6;   // e-quarter (64 elems)
    const int mt = i >> 4, l16 = i & 15;
    const half8* src = (const half8*)(qh + (size_t)(sq0 + i) * D_DIM + qtr * 64);
    #pragma unroll
    for (int u = 0; u < 8; ++u) {
        const int eb   = qtr * 8 + u;           // e-block (8 halfs) 0..31
        const int kk   = eb >> 2, quad = eb & 3;
        const int addr16 = (mt * 8 + kk) * 64 + quad * 16 + l16;
        *(half8*)(Afrag + addr16 * 8) = src[u];
    }
}

// Same layout for a 16-row tile (mt==0), 2 half8 per thread.
__device__ __forceinline__ void stage_q16(const _Float16* __restrict__ qh,
                                          _Float16* __restrict__ Afrag,
                                          int sq0, int tid)
{
    const int i  = tid & 15;    // row within tile (== l16)
    const int sx = tid >> 4;    // e-sixteenth (16 halfs = 2 half8)
    const half8* src = (const half8*)(qh + (size_t)(sq0 + i) * D_DIM);
    #pragma unroll
    for (int u = 0; u < 2; ++u) {
        const int eb   = sx * 2 + u;            // e-block (8 halfs) 0..31
        const int kk   = eb >> 2, quad = eb & 3;
        const int addr16 = kk * 64 + quad * 16 + i;
        *(half8*)(Afrag + addr16 * 8) = src[eb];
    }
}

// ---------------------------------------------------------------------------
// Stats: per-(sk,d) tile-partial (max, sum |L| e^(L-max)) over 64 sq rows.
// Grid (8 sq-tiles, 2 d-halves, 64 sk-chunks of 8) = 1024 blocks = 4/CU
// (was 32 chunks of 16 = 512 blocks = 2/CU; VGPR=128 + 32KB LDS allow 4).
// kk loop FULLY unrolled (wl must stay in VGPRs — partial unroll demotes it
// to scratch, the R7-R9 bug).
// ---------------------------------------------------------------------------
__global__ __launch_bounds__(256, 2) void stats_mfma(
    const _Float16* __restrict__ qh, const _Float16* __restrict__ kh,
    const _Float16* __restrict__ WlhT, const float* __restrict__ bl,
    float* __restrict__ pm, float* __restrict__ ps)
{
    __shared__ _Float16 Afrag[32 * 64 * 8];   // 32 KB

    const int tid  = threadIdx.x;
    const int lane = tid & 63, wave = tid >> 6;
    const int quad = lane >> 4, l16 = lane & 15;
    const int sqt  = blockIdx.x, sq0 = sqt * 64;
    const int dw   = blockIdx.y * 128 + wave * 32;
    const int sk0  = blockIdx.z * 8;

    stage_q(qh, Afrag, sq0, tid);

    half8 wl[2][8];
    #pragma unroll
    for (int nt = 0; nt < 2; ++nt) {
        const int d = dw + nt * 16 + l16;
        #pragma unroll
        for (int kk = 0; kk < 8; ++kk)
            wl[nt][kk] = *(const half8*)(WlhT + (size_t)d * D_DIM + kk * 32 + quad * 8);
    }
    float bl_r[2];
    #pragma unroll
    for (int nt = 0; nt < 2; ++nt)
        bl_r[nt] = bl[dw + nt * 16 + l16];

    __syncthreads();

    #pragma unroll 1
    for (int s = 0; s < 8; ++s) {
        const int sk = sk0 + s;
        floatx4 acc[4][2];
        #pragma unroll
        for (int mt = 0; mt < 4; ++mt)
            #pragma unroll
            for (int nt = 0; nt < 2; ++nt)
                acc[mt][nt] = (floatx4){0.f, 0.f, 0.f, 0.f};

        #pragma unroll
        for (int kk = 0; kk < 8; ++kk) {
            const half8 k8 = *(const half8*)(kh + (size_t)sk * D_DIM + kk * 32 + quad * 8);
            half8 af[4], bf[2];
            #pragma unroll
            for (int mt = 0; mt < 4; ++mt)
                af[mt] = *(const half8*)(Afrag + ((mt * 8 + kk) * 64 + lane) * 8);
            #pragma unroll
            for (int nt = 0; nt < 2; ++nt)
                bf[nt] = wl[nt][kk] * k8;
            #pragma unroll
            for (int mt = 0; mt < 4; ++mt)
                #pragma unroll
                for (int nt = 0; nt < 2; ++nt)
                    acc[mt][nt] = __builtin_amdgcn_mfma_f32_16x16x32_f16(
                        af[mt], bf[nt], acc[mt][nt], 0, 0, 0);
        }

        #pragma unroll
        for (int nt = 0; nt < 2; ++nt) {
            float Lv[4][4];
            float tmax = -1e30f;
            #pragma unroll
            for (int mt = 0; mt < 4; ++mt)
                #pragma unroll
                for (int r = 0; r < 4; ++r) {
                    const float L = acc[mt][nt][r] + bl_r[nt];
                    Lv[mt][r] = L;
                    tmax = fmaxf(tmax, L);
                }
            float tsum = 0.f;
            #pragma unroll
            for (int mt = 0; mt < 4; ++mt)
                #pragma unroll
                for (int r = 0; r < 4; ++r)
                    tsum += fabsf(Lv[mt][r]) * __expf(Lv[mt][r] - tmax);

            float m = tmax, ss = tsum;
            #pragma unroll
            for (int mask = 16; mask <= 32; mask <<= 1) {
                float m2 = __shfl_xor(m, mask, 64);
                float s2 = __shfl_xor(ss, mask, 64);
                float M  = fmaxf(m, m2);
                ss = ss * __expf(m - M) + s2 * __expf(m2 - M);
                m = M;
            }
            if (quad == 0) {
                const int d = dw + nt * 16 + l16;
                pm[((size_t)sqt * S_LEN + sk) * D_DIM + d] = m;
                ps[((size_t)sqt * S_LEN + sk) * D_DIM + d] = ss;
            }
        }
    }
}

// ---------------------------------------------------------------------------
// Merge the 8 sq-tile partials -> mbuf, sbuf.
// Tree-max first, then ONE exp pass: 8 exps instead of 14, shallow chain,
// all 16 loads issued up-front for MLP.
// ---------------------------------------------------------------------------
__global__ __launch_bounds__(256) void reduce_ms(
    const float* __restrict__ pm, const float* __restrict__ ps,
    float* __restrict__ mbuf, float* __restrict__ sbuf)
{
    const int idx = blockIdx.x * 256 + threadIdx.x;   // (sk,d), 131072 total
    float mv[8], sv[8];
    #pragma unroll
    for (int t = 0; t < 8; ++t) {
        mv[t] = pm[(size_t)t * SLICE + idx];
        sv[t] = ps[(size_t)t * SLICE + idx];
    }
    float M = mv[0];
    #pragma unroll
    for (int t = 1; t < 8; ++t) M = fmaxf(M, mv[t]);
    float ss = 0.f;
    #pragma unroll
    for (int t = 0; t < 8; ++t) ss += sv[t] * __expf(mv[t] - M);
    mbuf[idx] = M;
    sbuf[idx] = ss;
}

// ---------------------------------------------------------------------------
// Accum: recompute L, p = L e^(L-m)/(S+1); o += v[sk,d]*p over 32 sk;
// PLAIN stores of the fp32 partial tile to po[chunk] (no atomics — 8.4M
// device RMW atomics were R7/R11's ~110 us floor).
// Grid (32 sq-tiles of 16, 2 d-halves, 16 sk-chunks of 32) = 1024 blocks
// = 4/CU (was 16 sq-tiles of 32 = 512 blocks = 2/CU). mt dimension removed:
// fewer VGPRs (wl 64 + o 8 + acc 8 + temps ~ well under 128), LDS 8 KB,
// total LDS traffic unchanged (half tile x twice the blocks).
// po layout/footprint unchanged (chunk still 0..15).
// kk loop FULLY unrolled (wl in VGPRs).
// ---------------------------------------------------------------------------
__global__ __launch_bounds__(256, 4) void accum_mfma(
    const _Float16* __restrict__ qh, const _Float16* __restrict__ kh,
    const _Float16* __restrict__ WlhT, const float* __restrict__ bl,
    const float* __restrict__ mbuf, const float* __restrict__ sbuf,
    const float* __restrict__ vbuf, float* __restrict__ po)
{
    __shared__ _Float16 Afrag[8 * 64 * 8];    // 8 KB

    const int tid  = threadIdx.x;
    const int lane = tid & 63, wave = tid >> 6;
    const int quad = lane >> 4, l16 = lane & 15;
    const int sq0  = blockIdx.x * 16;
    const int dw   = blockIdx.y * 128 + wave * 32;
    const int chunk = blockIdx.z;
    const int sk0  = chunk * 32;

    stage_q16(qh, Afrag, sq0, tid);

    half8 wl[2][8];
    #pragma unroll
    for (int nt = 0; nt < 2; ++nt) {
        const int d = dw + nt * 16 + l16;
        #pragma unroll
        for (int kk = 0; kk < 8; ++kk)
            wl[nt][kk] = *(const half8*)(WlhT + (size_t)d * D_DIM + kk * 32 + quad * 8);
    }
    float bl_r[2];
    #pragma unroll
    for (int nt = 0; nt < 2; ++nt)
        bl_r[nt] = bl[dw + nt * 16 + l16];

    floatx4 o[2];
    #pragma unroll
    for (int nt = 0; nt < 2; ++nt)
        o[nt] = (floatx4){0.f, 0.f, 0.f, 0.f};

    __syncthreads();

    #pragma unroll 1
    for (int s = 0; s < 32; ++s) {
        const int sk = sk0 + s;
        floatx4 acc[2];
        #pragma unroll
        for (int nt = 0; nt < 2; ++nt)
            acc[nt] = (floatx4){0.f, 0.f, 0.f, 0.f};

        #pragma unroll
        for (int kk = 0; kk < 8; ++kk) {
            const half8 k8 = *(const half8*)(kh + (size_t)sk * D_DIM + kk * 32 + quad * 8);
            const half8 af = *(const half8*)(Afrag + (kk * 64 + lane) * 8);
            half8 bf[2];
            #pragma unroll
            for (int nt = 0; nt < 2; ++nt)
                bf[nt] = wl[nt][kk] * k8;
            #pragma unroll
            for (int nt = 0; nt < 2; ++nt)
                acc[nt] = __builtin_amdgcn_mfma_f32_16x16x32_f16(
                    af, bf[nt], acc[nt], 0, 0, 0);
        }

        #pragma unroll
        for (int nt = 0; nt < 2; ++nt) {
            const int d = dw + nt * 16 + l16;
            const float m_r = mbuf[(size_t)sk * D_DIM + d];
            const float inv = 1.0f / (sbuf[(size_t)sk * D_DIM + d] + 1.0f);
            const float vv  = vbuf[(size_t)sk * D_DIM + d];
            #pragma unroll
            for (int r = 0; r < 4; ++r) {
                const float L = acc[nt][r] + bl_r[nt];
                const float p = L * __expf(L - m_r) * inv;
                o[nt][r] += vv * p;
            }
        }
    }

    float* dst = po + (size_t)chunk * SLICE;
    #pragma unroll
    for (int nt = 0; nt < 2; ++nt)
        #pragma unroll
        for (int r = 0; r < 4; ++r) {
            const int row = sq0 + quad * 4 + r;
            const int col = dw + nt * 16 + l16;
            dst[(size_t)row * D_DIM + col] = o[nt][r];
        }
}

// ---------------------------------------------------------------------------
extern "C" void kernel_launch(void* const* d_in, const int* in_sizes, int n_in,
                              void* d_out, int out_size, void* d_ws, size_t ws_size,
                              hipStream_t stream)
{
    const float* query = (const float*)d_in[0];
    const float* key   = (const float*)d_in[1];
    const float* value = (const float*)d_in[2];
    const float* Wk  = (const float*)d_in[3];
    const float* bk  = (const float*)d_in[4];
    const float* Wq  = (const float*)d_in[5];
    const float* bq  = (const float*)d_in[6];
    const float* Wva = (const float*)d_in[7];
    const float* bva = (const float*)d_in[8];
    const float* Wl  = (const float*)d_in[9];
    const float* bl  = (const float*)d_in[10];
    const float* Wvo = (const float*)d_in[11];
    const float* bvo = (const float*)d_in[12];

    const int MAT = SLICE;                    // 131072
    float* ws   = (float*)d_ws;
    // R11-proven footprint kept (kbuf/qbuf fp32 slots now unused — linres3
    // writes kh/qh fp16 directly).
    float* vbuf = ws + 2 * MAT;
    float* mbuf = ws + 3 * MAT;
    float* sbuf = ws + 4 * MAT;
    _Float16* WlhT = (_Float16*)(ws + 6 * MAT);            // 128 KB
    _Float16* kh   = (_Float16*)(ws + 6 * MAT + 32768);    // 256 KB
    _Float16* qh   = kh + MAT;                             // 256 KB
    float* pm  = ws + 6 * MAT + 32768 + 2 * 65536;         // 4 MB
    float* ps  = pm + 8 * MAT;                             // 4 MB
    float* po  = pm;   // 16*MAT floats (8 MB), pm/ps dead after reduce_ms
    float* out = (float*)d_out;

    prep_wl<<<256, 256, 0, stream>>>(Wl, WlhT);
    linres3<<<dim3(256, 3), 256, 0, stream>>>(key, Wk, bk, kh,
                                              query, Wq, bq, qh,
                                              value, Wva, bva, vbuf);

    stats_mfma<<<dim3(8, 2, 64), 256, 0, stream>>>(qh, kh, WlhT, bl, pm, ps);
    reduce_ms<<<512, 256, 0, stream>>>(pm, ps, mbuf, sbuf);
    accum_mfma<<<dim3(32, 2, 16), 256, 0, stream>>>(qh, kh, WlhT, bl,
                                                    mbuf, sbuf, vbuf, po);

    linres_sum<<<256, 256, 0, stream>>>(po, Wvo, bvo, out);
}

// Round 2
// 215.216 us; speedup vs baseline: 1.3945x; 1.3945x over previous
//
#include <hip/hip_runtime.h>
#include <math.h>

#define S_LEN 512
#define D_DIM 256
#define SLICE (S_LEN * D_DIM)   // 131072

typedef _Float16 half8  __attribute__((ext_vector_type(8)));
typedef _Float16 half4v __attribute__((ext_vector_type(4)));
typedef float   floatx4 __attribute__((ext_vector_type(4)));

// ---------------------------------------------------------------------------
// WlhT[d][e] = fp16(Wl[e][d] + (e==d))     (raw + raw@Wl == raw@(I+Wl))
// ---------------------------------------------------------------------------
__global__ __launch_bounds__(256) void prep_wl(const float* __restrict__ Wl,
                                               _Float16* __restrict__ WlhT)
{
    const int d = blockIdx.x, e = threadIdx.x;
    float v = Wl[e * D_DIM + d] + (e == d ? 1.0f : 0.0f);
    WlhT[d * D_DIM + e] = (_Float16)v;
}

// ---------------------------------------------------------------------------
// y = x + x@W + b  for [512,256]@[256,256]; 4 rows/block (baseline shape —
// 2-row blocks double W refetch, regressed in R-round0).
// k,q results are consumed ONLY as fp16 downstream -> cast at the store
// (identical rounding to the old fp32-store + cvt kernel). v stays fp32.
// ---------------------------------------------------------------------------
__global__ __launch_bounds__(256) void linres3(
    const float* __restrict__ xk, const float* __restrict__ Wk,
    const float* __restrict__ bk, _Float16* __restrict__ yk16,
    const float* __restrict__ xq, const float* __restrict__ Wq,
    const float* __restrict__ bq, _Float16* __restrict__ yq16,
    const float* __restrict__ xv, const float* __restrict__ Wv,
    const float* __restrict__ bv, float* __restrict__ yv)
{
    __shared__ float xs[4][D_DIM];
    const int r0 = blockIdx.x * 4;
    const int sel = blockIdx.y;
    const float* x = sel == 0 ? xk : (sel == 1 ? xq : xv);
    const float* W = sel == 0 ? Wk : (sel == 1 ? Wq : Wv);
    const float* b = sel == 0 ? bk : (sel == 1 ? bq : bv);

    const int tid = threadIdx.x;
    #pragma unroll
    for (int t = 0; t < 4; ++t) xs[t][tid] = x[(r0 + t) * D_DIM + tid];
    __syncthreads();
    const float bv_ = b[tid];
    float acc[4];
    #pragma unroll
    for (int i = 0; i < 4; ++i) acc[i] = xs[i][tid] + bv_;
    #pragma unroll 4
    for (int e = 0; e < D_DIM; ++e) {
        const float w = W[e * D_DIM + tid];
        #pragma unroll
        for (int i = 0; i < 4; ++i) acc[i] += xs[i][e] * w;
    }
    if (sel == 2) {
        #pragma unroll
        for (int i = 0; i < 4; ++i) yv[(r0 + i) * D_DIM + tid] = acc[i];
    } else {
        _Float16* y16 = sel == 0 ? yk16 : yq16;
        #pragma unroll
        for (int i = 0; i < 4; ++i) y16[(r0 + i) * D_DIM + tid] = (_Float16)acc[i];
    }
}

// ---------------------------------------------------------------------------
// Final linear with partial-sum fusion: x = sum_c po[c]; out = x + x@W + b
// (baseline 4-row shape, proven)
// ---------------------------------------------------------------------------
__global__ __launch_bounds__(256) void linres_sum(
    const float* __restrict__ po, const float* __restrict__ W,
    const float* __restrict__ b, float* __restrict__ y)
{
    __shared__ float xs[4][D_DIM];
    const int tid = threadIdx.x;
    const int r0  = blockIdx.x * 4;
    #pragma unroll
    for (int t = 0; t < 4; ++t) {
        float s = 0.f;
        #pragma unroll
        for (int c = 0; c < 16; ++c)
            s += po[(size_t)c * SLICE + (r0 + t) * D_DIM + tid];
        xs[t][tid] = s;
    }
    __syncthreads();
    const float bv_ = b[tid];
    float acc[4];
    #pragma unroll
    for (int i = 0; i < 4; ++i) acc[i] = xs[i][tid] + bv_;
    #pragma unroll 4
    for (int e = 0; e < D_DIM; ++e) {
        const float w = W[e * D_DIM + tid];
        #pragma unroll
        for (int i = 0; i < 4; ++i) acc[i] += xs[i][e] * w;
    }
    #pragma unroll
    for (int i = 0; i < 4; ++i) y[(r0 + i) * D_DIM + tid] = acc[i];
}

// ---------------------------------------------------------------------------
// Stage 64x256 fp16 q tile into fragment-major LDS (R3/R7/R11-proven):
// fb = mt*8+kk; slot = quad*16+l16; addr16 = fb*64 + slot. Conflict-free.
// ---------------------------------------------------------------------------
__device__ __forceinline__ void stage_q(const _Float16* __restrict__ qh,
                                        _Float16* __restrict__ Afrag,
                                        int sq0, int tid)
{
    const int i   = tid & 63;   // row within tile
    const int qtr = tid >> 6;   // e-quarter (64 elems)
    const int mt = i >> 4, l16 = i & 15;
    const half8* src = (const half8*)(qh + (size_t)(sq0 + i) * D_DIM + qtr * 64);
    #pragma unroll
    for (int u = 0; u < 8; ++u) {
        const int eb   = qtr * 8 + u;           // e-block (8 halfs) 0..31
        const int kk   = eb >> 2, quad = eb & 3;
        const int addr16 = (mt * 8 + kk) * 64 + quad * 16 + l16;
        *(half8*)(Afrag + addr16 * 8) = src[u];
    }
}

// Same layout for a 32-row tile (mt in {0,1}), 4 half8 per thread (R8-proven).
__device__ __forceinline__ void stage_q32(const _Float16* __restrict__ qh,
                                          _Float16* __restrict__ Afrag,
                                          int sq0, int tid)
{
    const int i   = tid & 31;   // row within tile
    const int oct = tid >> 5;   // e-eighth (32 halfs)
    const int mt = i >> 4, l16 = i & 15;
    const half8* src = (const half8*)(qh + (size_t)(sq0 + i) * D_DIM);
    #pragma unroll
    for (int u = 0; u < 4; ++u) {
        const int eb   = oct * 4 + u;           // e-block (8 halfs) 0..31
        const int kk   = eb >> 2, quad = eb & 3;
        const int addr16 = (mt * 8 + kk) * 64 + quad * 16 + l16;
        *(half8*)(Afrag + addr16 * 8) = src[eb];
    }
}

// ---------------------------------------------------------------------------
// Stats: per-(sk,d) tile-partial (max, sum |L| e^(L-max)) over 64 sq rows.
// Grid (8 sq-tiles, 2 d-halves, 32 sk-chunks of 16) — BASELINE shape.
// R-round0 lesson: finer sk split (64 chunks of 8) regressed — per-block
// q-staging stops amortizing; occupancy was NOT the binding constraint.
// kk loop FULLY unrolled (wl must stay in VGPRs — partial unroll demotes it
// to scratch, the R7-R9 bug).
// ---------------------------------------------------------------------------
__global__ __launch_bounds__(256, 2) void stats_mfma(
    const _Float16* __restrict__ qh, const _Float16* __restrict__ kh,
    const _Float16* __restrict__ WlhT, const float* __restrict__ bl,
    float* __restrict__ pm, float* __restrict__ ps)
{
    __shared__ _Float16 Afrag[32 * 64 * 8];   // 32 KB

    const int tid  = threadIdx.x;
    const int lane = tid & 63, wave = tid >> 6;
    const int quad = lane >> 4, l16 = lane & 15;
    const int sqt  = blockIdx.x, sq0 = sqt * 64;
    const int dw   = blockIdx.y * 128 + wave * 32;
    const int sk0  = blockIdx.z * 16;

    stage_q(qh, Afrag, sq0, tid);

    half8 wl[2][8];
    #pragma unroll
    for (int nt = 0; nt < 2; ++nt) {
        const int d = dw + nt * 16 + l16;
        #pragma unroll
        for (int kk = 0; kk < 8; ++kk)
            wl[nt][kk] = *(const half8*)(WlhT + (size_t)d * D_DIM + kk * 32 + quad * 8);
    }
    float bl_r[2];
    #pragma unroll
    for (int nt = 0; nt < 2; ++nt)
        bl_r[nt] = bl[dw + nt * 16 + l16];

    __syncthreads();

    #pragma unroll 1
    for (int s = 0; s < 16; ++s) {
        const int sk = sk0 + s;
        floatx4 acc[4][2];
        #pragma unroll
        for (int mt = 0; mt < 4; ++mt)
            #pragma unroll
            for (int nt = 0; nt < 2; ++nt)
                acc[mt][nt] = (floatx4){0.f, 0.f, 0.f, 0.f};

        #pragma unroll
        for (int kk = 0; kk < 8; ++kk) {
            const half8 k8 = *(const half8*)(kh + (size_t)sk * D_DIM + kk * 32 + quad * 8);
            half8 af[4], bf[2];
            #pragma unroll
            for (int mt = 0; mt < 4; ++mt)
                af[mt] = *(const half8*)(Afrag + ((mt * 8 + kk) * 64 + lane) * 8);
            #pragma unroll
            for (int nt = 0; nt < 2; ++nt)
                bf[nt] = wl[nt][kk] * k8;
            #pragma unroll
            for (int mt = 0; mt < 4; ++mt)
                #pragma unroll
                for (int nt = 0; nt < 2; ++nt)
                    acc[mt][nt] = __builtin_amdgcn_mfma_f32_16x16x32_f16(
                        af[mt], bf[nt], acc[mt][nt], 0, 0, 0);
        }

        #pragma unroll
        for (int nt = 0; nt < 2; ++nt) {
            float Lv[4][4];
            float tmax = -1e30f;
            #pragma unroll
            for (int mt = 0; mt < 4; ++mt)
                #pragma unroll
                for (int r = 0; r < 4; ++r) {
                    const float L = acc[mt][nt][r] + bl_r[nt];
                    Lv[mt][r] = L;
                    tmax = fmaxf(tmax, L);
                }
            float tsum = 0.f;
            #pragma unroll
            for (int mt = 0; mt < 4; ++mt)
                #pragma unroll
                for (int r = 0; r < 4; ++r)
                    tsum += fabsf(Lv[mt][r]) * __expf(Lv[mt][r] - tmax);

            float m = tmax, ss = tsum;
            #pragma unroll
            for (int mask = 16; mask <= 32; mask <<= 1) {
                float m2 = __shfl_xor(m, mask, 64);
                float s2 = __shfl_xor(ss, mask, 64);
                float M  = fmaxf(m, m2);
                ss = ss * __expf(m - M) + s2 * __expf(m2 - M);
                m = M;
            }
            if (quad == 0) {
                const int d = dw + nt * 16 + l16;
                pm[((size_t)sqt * S_LEN + sk) * D_DIM + d] = m;
                ps[((size_t)sqt * S_LEN + sk) * D_DIM + d] = ss;
            }
        }
    }
}

// ---------------------------------------------------------------------------
// Merge the 8 sq-tile partials -> mbuf, sbuf.
// Tree-max first, then ONE exp pass: 8 exps instead of 14, shallow chain.
// ---------------------------------------------------------------------------
__global__ __launch_bounds__(256) void reduce_ms(
    const float* __restrict__ pm, const float* __restrict__ ps,
    float* __restrict__ mbuf, float* __restrict__ sbuf)
{
    const int idx = blockIdx.x * 256 + threadIdx.x;   // (sk,d), 131072 total
    float mv[8], sv[8];
    #pragma unroll
    for (int t = 0; t < 8; ++t) {
        mv[t] = pm[(size_t)t * SLICE + idx];
        sv[t] = ps[(size_t)t * SLICE + idx];
    }
    float M = mv[0];
    #pragma unroll
    for (int t = 1; t < 8; ++t) M = fmaxf(M, mv[t]);
    float ss = 0.f;
    #pragma unroll
    for (int t = 0; t < 8; ++t) ss += sv[t] * __expf(mv[t] - M);
    mbuf[idx] = M;
    sbuf[idx] = ss;
}

// ---------------------------------------------------------------------------
// Accum: recompute L, p = L e^(L-m)/(S+1); o += v[sk,d]*p over 32 sk;
// PLAIN stores of the 32x128 fp32 partial tile to po[chunk].
// Grid (16 sq-tiles of 32, 2 d-halves, 16 sk-chunks of 32) = 512 blocks —
// BASELINE shape (R-round0's sq split to 16-row tiles regressed 2.3x:
// duplicated N-side work, MfmaUtil 10%).
// NEW vs baseline: the per-(sk,d) epilogue scalars (mbuf/sbuf/vbuf) are
// loaded BEFORE the kk MFMA loop and pre-folded into w = vv/(s+1), so
// their ~200cy L2 latency hides under the 32-MFMA burst instead of
// stalling the exp epilogue.
// kk loop FULLY unrolled (wl in VGPRs).
// ---------------------------------------------------------------------------
__global__ __launch_bounds__(256, 2) void accum_mfma(
    const _Float16* __restrict__ qh, const _Float16* __restrict__ kh,
    const _Float16* __restrict__ WlhT, const float* __restrict__ bl,
    const float* __restrict__ mbuf, const float* __restrict__ sbuf,
    const float* __restrict__ vbuf, float* __restrict__ po)
{
    __shared__ _Float16 Afrag[16 * 64 * 8];   // 16 KB

    const int tid  = threadIdx.x;
    const int lane = tid & 63, wave = tid >> 6;
    const int quad = lane >> 4, l16 = lane & 15;
    const int sq0  = blockIdx.x * 32;
    const int dw   = blockIdx.y * 128 + wave * 32;
    const int chunk = blockIdx.z;
    const int sk0  = chunk * 32;

    stage_q32(qh, Afrag, sq0, tid);

    half8 wl[2][8];
    #pragma unroll
    for (int nt = 0; nt < 2; ++nt) {
        const int d = dw + nt * 16 + l16;
        #pragma unroll
        for (int kk = 0; kk < 8; ++kk)
            wl[nt][kk] = *(const half8*)(WlhT + (size_t)d * D_DIM + kk * 32 + quad * 8);
    }
    float bl_r[2];
    #pragma unroll
    for (int nt = 0; nt < 2; ++nt)
        bl_r[nt] = bl[dw + nt * 16 + l16];

    floatx4 o[2][2];
    #pragma unroll
    for (int mt = 0; mt < 2; ++mt)
        #pragma unroll
        for (int nt = 0; nt < 2; ++nt)
            o[mt][nt] = (floatx4){0.f, 0.f, 0.f, 0.f};

    __syncthreads();

    #pragma unroll 1
    for (int s = 0; s < 32; ++s) {
        const int sk = sk0 + s;

        // ---- hoisted epilogue scalars: issue loads before the MFMA burst
        float m_r2[2], w_r2[2];
        #pragma unroll
        for (int nt = 0; nt < 2; ++nt) {
            const int d = dw + nt * 16 + l16;
            m_r2[nt] = mbuf[(size_t)sk * D_DIM + d];
            const float sden = sbuf[(size_t)sk * D_DIM + d];
            const float vv   = vbuf[(size_t)sk * D_DIM + d];
            w_r2[nt] = vv / (sden + 1.0f);
        }

        floatx4 acc[2][2];
        #pragma unroll
        for (int mt = 0; mt < 2; ++mt)
            #pragma unroll
            for (int nt = 0; nt < 2; ++nt)
                acc[mt][nt] = (floatx4){0.f, 0.f, 0.f, 0.f};

        #pragma unroll
        for (int kk = 0; kk < 8; ++kk) {
            const half8 k8 = *(const half8*)(kh + (size_t)sk * D_DIM + kk * 32 + quad * 8);
            half8 af[2], bf[2];
            #pragma unroll
            for (int mt = 0; mt < 2; ++mt)
                af[mt] = *(const half8*)(Afrag + ((mt * 8 + kk) * 64 + lane) * 8);
            #pragma unroll
            for (int nt = 0; nt < 2; ++nt)
                bf[nt] = wl[nt][kk] * k8;
            #pragma unroll
            for (int mt = 0; mt < 2; ++mt)
                #pragma unroll
                for (int nt = 0; nt < 2; ++nt)
                    acc[mt][nt] = __builtin_amdgcn_mfma_f32_16x16x32_f16(
                        af[mt], bf[nt], acc[mt][nt], 0, 0, 0);
        }

        #pragma unroll
        for (int nt = 0; nt < 2; ++nt) {
            const float m_r = m_r2[nt];
            const float w_r = w_r2[nt];
            #pragma unroll
            for (int mt = 0; mt < 2; ++mt)
                #pragma unroll
                for (int r = 0; r < 4; ++r) {
                    const float L = acc[mt][nt][r] + bl_r[nt];
                    const float t = __expf(L - m_r);
                    o[mt][nt][r] += w_r * (L * t);
                }
        }
    }

    float* dst = po + (size_t)chunk * SLICE;
    #pragma unroll
    for (int mt = 0; mt < 2; ++mt)
        #pragma unroll
        for (int nt = 0; nt < 2; ++nt)
            #pragma unroll
            for (int r = 0; r < 4; ++r) {
                const int row = sq0 + mt * 16 + quad * 4 + r;
                const int col = dw + nt * 16 + l16;
                dst[(size_t)row * D_DIM + col] = o[mt][nt][r];
            }
}

// ---------------------------------------------------------------------------
extern "C" void kernel_launch(void* const* d_in, const int* in_sizes, int n_in,
                              void* d_out, int out_size, void* d_ws, size_t ws_size,
                              hipStream_t stream)
{
    const float* query = (const float*)d_in[0];
    const float* key   = (const float*)d_in[1];
    const float* value = (const float*)d_in[2];
    const float* Wk  = (const float*)d_in[3];
    const float* bk  = (const float*)d_in[4];
    const float* Wq  = (const float*)d_in[5];
    const float* bq  = (const float*)d_in[6];
    const float* Wva = (const float*)d_in[7];
    const float* bva = (const float*)d_in[8];
    const float* Wl  = (const float*)d_in[9];
    const float* bl  = (const float*)d_in[10];
    const float* Wvo = (const float*)d_in[11];
    const float* bvo = (const float*)d_in[12];

    const int MAT = SLICE;                    // 131072
    float* ws   = (float*)d_ws;
    // R11-proven footprint (kbuf/qbuf fp32 slots now unused — linres3
    // writes kh/qh fp16 directly).
    float* vbuf = ws + 2 * MAT;
    float* mbuf = ws + 3 * MAT;
    float* sbuf = ws + 4 * MAT;
    _Float16* WlhT = (_Float16*)(ws + 6 * MAT);            // 128 KB
    _Float16* kh   = (_Float16*)(ws + 6 * MAT + 32768);    // 256 KB
    _Float16* qh   = kh + MAT;                             // 256 KB
    float* pm  = ws + 6 * MAT + 32768 + 2 * 65536;         // 4 MB
    float* ps  = pm + 8 * MAT;                             // 4 MB
    float* po  = pm;   // 16*MAT floats (8 MB), pm/ps dead after reduce_ms
    float* out = (float*)d_out;

    prep_wl<<<256, 256, 0, stream>>>(Wl, WlhT);
    linres3<<<dim3(128, 3), 256, 0, stream>>>(key, Wk, bk, kh,
                                              query, Wq, bq, qh,
                                              value, Wva, bva, vbuf);

    stats_mfma<<<dim3(8, 2, 32), 256, 0, stream>>>(qh, kh, WlhT, bl, pm, ps);
    reduce_ms<<<512, 256, 0, stream>>>(pm, ps, mbuf, sbuf);
    accum_mfma<<<dim3(16, 2, 16), 256, 0, stream>>>(qh, kh, WlhT, bl,
                                                    mbuf, sbuf, vbuf, po);

    linres_sum<<<128, 256, 0, stream>>>(po, Wvo, bvo, out);
}